// Round 11
// baseline (151.575 us; speedup 1.0000x reference)
//
#include <hip/hip_runtime.h>
#include <math.h>

// OnlineTripletLoss on MI355X — Round 11.
// R10: 139 us (fused 82.8, MFMA busy ~21 us = floor, ~56 us prep+launch overhead).
// Changes:
//  (1) SYMMETRY: dist matrix is symmetric -> compute only upper-triangle tiles
//      (528 x 128x128). Off-diag tiles contribute row-side stats (anchors in py)
//      AND col-side stats (anchors in px). MFMA floor 21 -> 10.3 us.
//      Col-side reduction via padded LDS transpose buffer [64][129] (conflict-free).
//      Barrier: panel p done when ctr[p] == 32 (each off-diag block arrives at 2 ctrs).
//      528 blocks at ~36 KB LDS -> 4 blocks/CU capacity => co-resident (no deadlock).
//  (2) prep: 256 blocks of 16 rows (was 128x32) -> full-GPU spread.
// ws: sq[N] | hp[N] | hn_fall[N] | hn_semi[N] | bars[1024] | pad | pan[N*2D] f16

constexpr float MARGIN = 0.3f;

typedef _Float16 half8    __attribute__((ext_vector_type(8)));
typedef float    floatx16 __attribute__((ext_vector_type(16)));

#define GLD_LDS16(gp, lp)                                                              \
    __builtin_amdgcn_global_load_lds(                                                  \
        (const __attribute__((address_space(1))) void*)(gp),                           \
        (__attribute__((address_space(3))) void*)(lp), 16, 0, 0)

// prep: 16 rows/block; builds pan[p][kc][r][8] (kc<64 hi, kc>=64 lo), sq, init, bars.
__global__ __launch_bounds__(256)
void prep_kernel(const float* __restrict__ e, _Float16* __restrict__ pan,
                 float* __restrict__ sq, unsigned int* __restrict__ hp,
                 unsigned int* __restrict__ hn_fall, unsigned int* __restrict__ hn_semi,
                 unsigned int* __restrict__ bars, int N, int D) {
    if (blockIdx.x == 0) {
        if (threadIdx.x < 32) bars[threadIdx.x * 32] = 0u;
        if (threadIdx.x == 32) bars[1023] = 0u;
    }
    const int r0  = blockIdx.x * 16;
    const int p   = r0 >> 7;
    const int rl  = r0 & 127;
    const int r   = threadIdx.x >> 4;     // 0..15
    const int c16 = threadIdx.x & 15;
    const int row = r0 + r;
    const float* er = e + (size_t)row * D;
    float s = 0.f;
    #pragma unroll
    for (int it = 0; it < 4; ++it) {
        const int kw = c16 + it * 16;     // 0..63 k-chunks of 8
        const float4 x0 = *(const float4*)&er[kw * 8];
        const float4 x1 = *(const float4*)&er[kw * 8 + 4];
        const float xv[8] = {x0.x, x0.y, x0.z, x0.w, x1.x, x1.y, x1.z, x1.w};
        half8 hi, lo;
        #pragma unroll
        for (int j = 0; j < 8; ++j) {
            _Float16 h = (_Float16)xv[j];
            hi[j] = h;
            lo[j] = (_Float16)(xv[j] - (float)h);
            s += xv[j] * xv[j];
        }
        *(half8*)&pan[((size_t)(p * 128 + kw) * 128 + rl + r) * 8]      = hi;
        *(half8*)&pan[((size_t)(p * 128 + 64 + kw) * 128 + rl + r) * 8] = lo;
    }
    s += __shfl_down(s, 8, 16);
    s += __shfl_down(s, 4, 16);
    s += __shfl_down(s, 2, 16);
    s += __shfl_down(s, 1, 16);
    if (c16 == 0) {
        sq[row]      = s;
        hp[row]      = 0u;           // max identity (dist >= 0)
        hn_fall[row] = 0u;
        hn_semi[row] = 0x7f800000u;  // +inf (min identity)
    }
}

// Fused symmetric kernel: upper-triangle tiles 128x128, 256 thr = 4 waves (2x2) of 64x64.
// Double-buffered DMA staging (BK=16), swapped-operand MFMA (rows in lanes).
__global__ __launch_bounds__(256, 4)
void fused_kernel(const _Float16* __restrict__ pan, const int* __restrict__ labels,
                  const float* __restrict__ sq,
                  unsigned int* __restrict__ hp,
                  unsigned int* __restrict__ hn_fall,
                  unsigned int* __restrict__ hn_semi,
                  unsigned int* __restrict__ bars,
                  float* __restrict__ out,
                  int N, int D, int nt, unsigned int nblocks) {
    // SMEM union: staging 2 x 8192 halves (32 KB)  |  colbuf [64][129] f32 (33 KB)
    __shared__ __attribute__((aligned(16))) unsigned char SMEM[33024];
    __shared__ float sq_r[128], sq_c[128], hp_r[128], hp_c[128];
    __shared__ int   lab_r[128], lab_c[128];
    __shared__ int   lastflag;
    _Float16* S      = (_Float16*)SMEM;
    float*    colbuf = (float*)SMEM;

    const int tid  = threadIdx.x;
    const int lane = tid & 63;
    const int wave = tid >> 6;            // 0..3
    const int wr = (wave >> 1) * 64;
    const int wc = (wave & 1) * 64;
    const int mrow = lane & 31;
    const int half_id = lane >> 5;

    // triangle mapping: blockIdx -> (py, px), py <= px
    int py = 0, rem = blockIdx.x;
    while (rem >= nt - py) { rem -= nt - py; ++py; }
    const int px = py + rem;
    const bool diag = (px == py);
    const int rowBase = py * 128, colBase = px * 128;

    if (tid < 128) {
        sq_r[tid]  = sq[rowBase + tid];
        lab_r[tid] = labels[rowBase + tid];
    } else {
        const int t = tid - 128;
        sq_c[t]  = sq[colBase + t];
        lab_c[t] = labels[colBase + t];
    }

    floatx16 acc[2][2];   // acc[bj][ai]: cols in regs (bj), rows in lanes (ai)
    #pragma unroll
    for (int a = 0; a < 2; ++a)
        #pragma unroll
        for (int b = 0; b < 2; ++b)
            #pragma unroll
            for (int r = 0; r < 16; ++r) acc[a][b][r] = 0.f;

    // staging: 16 slabs of 1KB per stage; wave w issues slabs 4w..4w+3
    auto stage = [&](int b, int kkv) {
        #pragma unroll
        for (int t = 0; t < 4; ++t) {
            const int slab = wave * 4 + t;          // 0..15
            const int side = slab >> 3;             // 0 = A(py), 1 = B(px)
            const int u = slab & 7;
            const int kcl = u >> 1, rh = u & 1;
            const int pp = side ? px : py;
            const int kc = (kcl < 2) ? (2 * kkv + kcl) : (64 + 2 * kkv + (kcl - 2));
            const _Float16* g = pan + ((size_t)(pp * 128 + kc) * 128 + rh * 64 + lane) * 8;
            GLD_LDS16(g, &S[b * 8192 + side * 4096 + (kcl * 128 + rh * 64) * 8]);
        }
    };

    stage(0, 0);
    #pragma unroll 1
    for (int kk = 0; kk < 32; ++kk) {
        const int b = kk & 1;
        __syncthreads();
        if (kk + 1 < 32) stage(b ^ 1, kk + 1);
        const _Float16* Sb = S + b * 8192;
        const int rA = wr + mrow, cB = wc + mrow;
        const half8 ah0 = *(const half8*)&Sb[(half_id * 128 + rA) * 8];
        const half8 ah1 = *(const half8*)&Sb[(half_id * 128 + rA + 32) * 8];
        const half8 al0 = *(const half8*)&Sb[((2 + half_id) * 128 + rA) * 8];
        const half8 al1 = *(const half8*)&Sb[((2 + half_id) * 128 + rA + 32) * 8];
        const half8 bh0 = *(const half8*)&Sb[4096 + (half_id * 128 + cB) * 8];
        const half8 bh1 = *(const half8*)&Sb[4096 + (half_id * 128 + cB + 32) * 8];
        const half8 bl0 = *(const half8*)&Sb[4096 + ((2 + half_id) * 128 + cB) * 8];
        const half8 bl1 = *(const half8*)&Sb[4096 + ((2 + half_id) * 128 + cB + 32) * 8];
        acc[0][0] = __builtin_amdgcn_mfma_f32_32x32x16_f16(bh0, ah0, acc[0][0], 0, 0, 0);
        acc[0][1] = __builtin_amdgcn_mfma_f32_32x32x16_f16(bh0, ah1, acc[0][1], 0, 0, 0);
        acc[1][0] = __builtin_amdgcn_mfma_f32_32x32x16_f16(bh1, ah0, acc[1][0], 0, 0, 0);
        acc[1][1] = __builtin_amdgcn_mfma_f32_32x32x16_f16(bh1, ah1, acc[1][1], 0, 0, 0);
        acc[0][0] = __builtin_amdgcn_mfma_f32_32x32x16_f16(bl0, ah0, acc[0][0], 0, 0, 0);
        acc[0][1] = __builtin_amdgcn_mfma_f32_32x32x16_f16(bl0, ah1, acc[0][1], 0, 0, 0);
        acc[1][0] = __builtin_amdgcn_mfma_f32_32x32x16_f16(bl1, ah0, acc[1][0], 0, 0, 0);
        acc[1][1] = __builtin_amdgcn_mfma_f32_32x32x16_f16(bl1, ah1, acc[1][1], 0, 0, 0);
        acc[0][0] = __builtin_amdgcn_mfma_f32_32x32x16_f16(bh0, al0, acc[0][0], 0, 0, 0);
        acc[0][1] = __builtin_amdgcn_mfma_f32_32x32x16_f16(bh0, al1, acc[0][1], 0, 0, 0);
        acc[1][0] = __builtin_amdgcn_mfma_f32_32x32x16_f16(bh1, al0, acc[1][0], 0, 0, 0);
        acc[1][1] = __builtin_amdgcn_mfma_f32_32x32x16_f16(bh1, al1, acc[1][1], 0, 0, 0);
    }
    __syncthreads();   // all waves done with S before colbuf reuse

    float sqr[2]; int labr[2];
    #pragma unroll
    for (int ai = 0; ai < 2; ++ai) {
        sqr[ai]  = sq_r[wr + ai * 32 + mrow];
        labr[ai] = lab_r[wr + ai * 32 + mrow];
    }
    auto distf = [&](int bj, int ai, int r, int c) {
        return sqrtf(fmaxf(sqr[ai] + sq_c[c] - 2.0f * acc[bj][ai][r], 1e-12f));
    };

    // ---- phase 1 row-side: hp / hn_fall for panel py ----
    #pragma unroll
    for (int ai = 0; ai < 2; ++ai) {
        float vp = 0.f, vn = 0.f;
        #pragma unroll
        for (int bj = 0; bj < 2; ++bj)
            #pragma unroll
            for (int r = 0; r < 16; ++r) {
                const int c = wc + bj * 32 + (r & 3) + 8 * (r >> 2) + 4 * half_id;
                const float d = distf(bj, ai, r, c);
                const bool pos = (labr[ai] == lab_c[c]);
                vp = fmaxf(vp, pos ? d : 0.f);
                vn = fmaxf(vn, pos ? 0.f : d);
            }
        vp = fmaxf(vp, __shfl_xor(vp, 32, 64));
        vn = fmaxf(vn, __shfl_xor(vn, 32, 64));
        if (half_id == 0) {
            atomicMax(&hp[rowBase + wr + ai * 32 + mrow],      __float_as_uint(vp));
            atomicMax(&hn_fall[rowBase + wr + ai * 32 + mrow], __float_as_uint(vn));
        }
    }

    // ---- phase 1 col-side (off-diag): anchors in panel px ----
    const int rr = (wave >> 1) * 32 + mrow;     // row index within colbuf
    if (!diag) {
        #pragma unroll
        for (int kind = 0; kind < 2; ++kind) {  // 0 = vp(pos max), 1 = vn(neg max)
            #pragma unroll
            for (int bj = 0; bj < 2; ++bj)
                #pragma unroll
                for (int r = 0; r < 16; ++r) {
                    const int c = wc + bj * 32 + (r & 3) + 8 * (r >> 2) + 4 * half_id;
                    const float d0 = distf(bj, 0, r, c);
                    const float d1 = distf(bj, 1, r, c);
                    const bool p0 = (labr[0] == lab_c[c]), p1 = (labr[1] == lab_c[c]);
                    float v;
                    if (kind == 0) v = fmaxf(p0 ? d0 : 0.f, p1 ? d1 : 0.f);
                    else           v = fmaxf(p0 ? 0.f : d0, p1 ? 0.f : d1);
                    colbuf[rr * 129 + c] = v;
                }
            __syncthreads();
            if (tid < 128) {
                float v = 0.f;
                #pragma unroll 4
                for (int q = 0; q < 64; ++q) v = fmaxf(v, colbuf[q * 129 + tid]);
                if (kind == 0) atomicMax(&hp[colBase + tid],      __float_as_uint(v));
                else           atomicMax(&hn_fall[colBase + tid], __float_as_uint(v));
            }
            __syncthreads();
        }
    }

    // ---- per-panel barrier: panel p complete at 32 arrivals ----
    __syncthreads();
    if (tid == 0) {
        __threadfence();
        atomicAdd(&bars[py * 32], 1u);
        if (!diag) atomicAdd(&bars[px * 32], 1u);
        while (__hip_atomic_load(&bars[py * 32], __ATOMIC_ACQUIRE, __HIP_MEMORY_SCOPE_AGENT)
               < (unsigned)nt) __builtin_amdgcn_s_sleep(32);
        while (__hip_atomic_load(&bars[px * 32], __ATOMIC_ACQUIRE, __HIP_MEMORY_SCOPE_AGENT)
               < (unsigned)nt) __builtin_amdgcn_s_sleep(32);
    }
    __syncthreads();
    if (tid < 128)
        hp_r[tid] = __uint_as_float(__hip_atomic_load(&hp[rowBase + tid],
                                    __ATOMIC_RELAXED, __HIP_MEMORY_SCOPE_AGENT));
    else {
        const int t = tid - 128;
        hp_c[t] = __uint_as_float(__hip_atomic_load(&hp[colBase + t],
                                  __ATOMIC_RELAXED, __HIP_MEMORY_SCOPE_AGENT));
    }
    __syncthreads();

    // ---- phase 2 row-side: hn_semi for panel py ----
    #pragma unroll
    for (int ai = 0; ai < 2; ++ai) {
        const float hpv = hp_r[wr + ai * 32 + mrow];
        float vm = __builtin_inff();
        #pragma unroll
        for (int bj = 0; bj < 2; ++bj)
            #pragma unroll
            for (int r = 0; r < 16; ++r) {
                const int c = wc + bj * 32 + (r & 3) + 8 * (r >> 2) + 4 * half_id;
                const float d = distf(bj, ai, r, c);
                const bool cand = (labr[ai] != lab_c[c]) && (d > hpv);
                vm = fminf(vm, cand ? d : __builtin_inff());
            }
        vm = fminf(vm, __shfl_xor(vm, 32, 64));
        if (half_id == 0)
            atomicMin(&hn_semi[rowBase + wr + ai * 32 + mrow], __float_as_uint(vm));
    }

    // ---- phase 2 col-side (off-diag): hn_semi for panel px ----
    if (!diag) {
        #pragma unroll
        for (int bj = 0; bj < 2; ++bj)
            #pragma unroll
            for (int r = 0; r < 16; ++r) {
                const int c = wc + bj * 32 + (r & 3) + 8 * (r >> 2) + 4 * half_id;
                const float hpv = hp_c[c];
                const float d0 = distf(bj, 0, r, c);
                const float d1 = distf(bj, 1, r, c);
                const bool c0 = (labr[0] != lab_c[c]) && (d0 > hpv);
                const bool c1 = (labr[1] != lab_c[c]) && (d1 > hpv);
                colbuf[rr * 129 + c] = fminf(c0 ? d0 : __builtin_inff(),
                                             c1 ? d1 : __builtin_inff());
            }
        __syncthreads();
        if (tid < 128) {
            float v = __builtin_inff();
            #pragma unroll 4
            for (int q = 0; q < 64; ++q) v = fminf(v, colbuf[q * 129 + tid]);
            atomicMin(&hn_semi[colBase + tid], __float_as_uint(v));
        }
    }

    // ---- last-block final reduction ----
    __syncthreads();
    if (tid == 0) {
        __threadfence();
        unsigned int old = atomicAdd(&bars[1023], 1u);
        lastflag = (old == nblocks - 1) ? 1 : 0;
    }
    __syncthreads();
    if (!lastflag) return;
    if (tid == 0) __threadfence();
    __syncthreads();

    float* FS = (float*)SMEM;       // 256 sums
    int*   IC = (int*)(FS + 256);   // 256 counts
    int*   IA = IC + 256;           // 256 any-flags
    int any = 0;
    for (int r = tid; r < N; r += 256) {
        float h  = __uint_as_float(__hip_atomic_load(&hp[r],      __ATOMIC_RELAXED, __HIP_MEMORY_SCOPE_AGENT));
        float hs = __uint_as_float(__hip_atomic_load(&hn_semi[r], __ATOMIC_RELAXED, __HIP_MEMORY_SCOPE_AGENT));
        any |= (hs < h + MARGIN) ? 1 : 0;
    }
    IA[tid] = any;
    __syncthreads();
    for (int s = 128; s; s >>= 1) {
        if (tid < s) IA[tid] |= IA[tid + s];
        __syncthreads();
    }
    const bool has_semi = IA[0] != 0;
    float sum = 0.f; int valid = 0;
    for (int r = tid; r < N; r += 256) {
        float h  = __uint_as_float(__hip_atomic_load(&hp[r], __ATOMIC_RELAXED, __HIP_MEMORY_SCOPE_AGENT));
        float hn = has_semi
            ? __uint_as_float(__hip_atomic_load(&hn_semi[r], __ATOMIC_RELAXED, __HIP_MEMORY_SCOPE_AGENT))
            : __uint_as_float(__hip_atomic_load(&hn_fall[r], __ATOMIC_RELAXED, __HIP_MEMORY_SCOPE_AGENT));
        float t = fmaxf(h - hn + MARGIN, 0.f);
        if (!(t > 0.f)) t = 0.f;        // -inf guard (hn=+inf rows)
        sum += t;
        valid += (t > 0.f) ? 1 : 0;
    }
    FS[tid] = sum; IC[tid] = valid;
    __syncthreads();
    for (int s = 128; s; s >>= 1) {
        if (tid < s) { FS[tid] += FS[tid + s]; IC[tid] += IC[tid + s]; }
        __syncthreads();
    }
    if (tid == 0) {
        float total = FS[0]; int v = IC[0];
        out[0] = (v > 0) ? (total / (float)v) : (total / (float)N);
    }
}

extern "C" void kernel_launch(void* const* d_in, const int* in_sizes, int n_in,
                              void* d_out, int out_size, void* d_ws, size_t ws_size,
                              hipStream_t stream) {
    const float* e      = (const float*)d_in[0];
    const int*   labels = (const int*)d_in[1];
    const int N = in_sizes[1];
    const int D = in_sizes[0] / N;
    float* out = (float*)d_out;

    float*        sq      = (float*)d_ws;
    unsigned int* hp      = (unsigned int*)d_ws + N;
    unsigned int* hn_fall = hp + N;
    unsigned int* hn_semi = hn_fall + N;
    unsigned int* bars    = hn_semi + N;     // 32 counters (128B-spaced) + done @1023

    const size_t small_bytes = ((size_t)(4 * N + 1024) * 4 + 255) & ~(size_t)255;
    _Float16* pan = (_Float16*)((char*)d_ws + small_bytes);

    prep_kernel<<<N / 16, 256, 0, stream>>>(e, pan, sq, hp, hn_fall, hn_semi, bars, N, D);

    const int nt = N / 128;                      // 32 panels
    const int nblocks = nt * (nt + 1) / 2;       // 528 upper-triangle tiles
    fused_kernel<<<nblocks, 256, 0, stream>>>(pan, labels, sq, hp, hn_fall, hn_semi,
                                              bars, out, N, D, nt, (unsigned)nblocks);
}

// Round 12
// 141.761 us; speedup vs baseline: 1.0692x; 1.0692x over previous
//
#include <hip/hip_runtime.h>
#include <math.h>

// OnlineTripletLoss on MI355X — Round 12.
// R11: triangle REGRESSED (fused 82.8 -> 99.1): col-side LDS epilogue + dual-counter
//      barrier + 528-block tail drain cost more than the halved MFMA floor (10.5 us,
//      confirmed by MfmaUtil). Reverted.
// R10 decomposition: total 139.1 = fused 82.8 + ~50 us PREP + ~6 us launches. Prep's
//      transpose stores are 16B-per-lane at 2KB stride -> 64 TA sub-transactions per
//      wave store (same scatter pathology as R5's DMA gather).
// Change (prep only; fused kernel byte-identical to R10):
//  LDS-staged transpose prep: 256 blocks x 16 rows; coalesced 2KB row loads ->
//  hi/lo convert -> padded LDS [kc][17] -> panel stores with 16 consecutive lanes
//  contiguous (256B chunks, ~8x fewer transactions). sq via 64-lane wave reduce.
// ws: sq[N] | hp[N] | hn_fall[N] | hn_semi[N] | bars[1024] | pad | pan[N*2D] f16

constexpr float MARGIN = 0.3f;

typedef _Float16 half8    __attribute__((ext_vector_type(8)));
typedef float    floatx16 __attribute__((ext_vector_type(16)));

#define GLD_LDS16(gp, lp)                                                              \
    __builtin_amdgcn_global_load_lds(                                                  \
        (const __attribute__((address_space(1))) void*)(gp),                           \
        (__attribute__((address_space(3))) void*)(lp), 16, 0, 0)

// prep v2: 16 rows/block, LDS-staged transpose. pan[p][kc][r][8], kc<64 hi, kc>=64 lo.
__global__ __launch_bounds__(256)
void prep_kernel(const float* __restrict__ e, _Float16* __restrict__ pan,
                 float* __restrict__ sq, unsigned int* __restrict__ hp,
                 unsigned int* __restrict__ hn_fall, unsigned int* __restrict__ hn_semi,
                 unsigned int* __restrict__ bars, int N, int D) {
    // [kc(64)][row(16) + 1 pad] half8s: pad keeps both LDS phases bank-uniform
    __shared__ __attribute__((aligned(16))) _Float16 Lhi[64 * 17 * 8];
    __shared__ __attribute__((aligned(16))) _Float16 Llo[64 * 17 * 8];

    if (blockIdx.x == 0 && threadIdx.x < 32) bars[threadIdx.x * 32] = 0u;

    const int tid = threadIdx.x;
    const int r0  = blockIdx.x * 16;
    const int p   = r0 >> 7;
    const int rl  = r0 & 127;

    float s[4];
    // ---- load (coalesced: wave = one row, 2KB) + convert + LDS write ----
    #pragma unroll
    for (int it = 0; it < 4; ++it) {
        const int idx = it * 256 + tid;
        const int row = idx >> 6;            // 0..15 (wave-uniform)
        const int seg = idx & 63;            // col chunk of 8
        const float* src = &e[(size_t)(r0 + row) * D + seg * 8];
        const float4 x0 = *(const float4*)src;
        const float4 x1 = *(const float4*)(src + 4);
        const float xv[8] = {x0.x, x0.y, x0.z, x0.w, x1.x, x1.y, x1.z, x1.w};
        half8 hi, lo;
        float acc = 0.f;
        #pragma unroll
        for (int j = 0; j < 8; ++j) {
            _Float16 h = (_Float16)xv[j];
            hi[j] = h;
            lo[j] = (_Float16)(xv[j] - (float)h);
            acc += xv[j] * xv[j];
        }
        s[it] = acc;
        *(half8*)&Lhi[(seg * 17 + row) * 8] = hi;
        *(half8*)&Llo[(seg * 17 + row) * 8] = lo;
    }
    __syncthreads();
    // ---- store (16 consecutive lanes -> 256B contiguous per kc) ----
    #pragma unroll
    for (int it = 0; it < 4; ++it) {
        const int idx = it * 256 + tid;
        const int kc  = idx >> 4;            // 0..63
        const int row = idx & 15;
        const half8 hi = *(const half8*)&Lhi[(kc * 17 + row) * 8];
        const half8 lo = *(const half8*)&Llo[(kc * 17 + row) * 8];
        *(half8*)&pan[((size_t)(p * 128 + kc) * 128 + rl + row) * 8]      = hi;
        *(half8*)&pan[((size_t)(p * 128 + 64 + kc) * 128 + rl + row) * 8] = lo;
    }
    // ---- sq + per-row init (wave reduce, lane 0 writes) ----
    #pragma unroll
    for (int it = 0; it < 4; ++it) {
        float v = s[it];
        #pragma unroll
        for (int off = 32; off; off >>= 1) v += __shfl_down(v, off, 64);
        if ((tid & 63) == 0) {
            const int row = r0 + it * 4 + (tid >> 6);
            sq[row]      = v;
            hp[row]      = 0u;           // max identity (dist >= 0)
            hn_fall[row] = 0u;
            hn_semi[row] = 0x7f800000u;  // +inf (min identity)
        }
    }
}

// Fused kernel (byte-identical to R10): tile 256(rows) x 128(cols), 512 thr = 8 waves
// (4x2) of 64x64. Double-buffered DMA staging (BK=16), swapped-operand MFMA,
// per-row-panel barrier, last-block final reduction.
__global__ __launch_bounds__(512, 4)
void fused_kernel(const _Float16* __restrict__ pan, const int* __restrict__ labels,
                  const float* __restrict__ sq,
                  unsigned int* __restrict__ hp,
                  unsigned int* __restrict__ hn_fall,
                  unsigned int* __restrict__ hn_semi,
                  unsigned int* __restrict__ bars,
                  float* __restrict__ out,
                  int N, int D, unsigned int nrowblocks, unsigned int nblocks) {
    __shared__ __attribute__((aligned(16))) _Float16 S[2][12288];   // 48 KB
    __shared__ float sq_r[256], sq_c[128], hp_r[256];
    __shared__ int   lab_r[256], lab_c[128];
    __shared__ int   lastflag;

    const int tid  = threadIdx.x;
    const int lane = tid & 63;
    const int wave = tid >> 6;            // 0..7
    const int wr = (wave >> 1) * 64;      // 0,64,128,192
    const int wc = (wave & 1) * 64;       // 0,64
    const int mrow = lane & 31;
    const int half_id = lane >> 5;

    const int j  = blockIdx.x & 7;
    const int i  = blockIdx.x >> 3;       // 0..63
    const int px = (j & 3) * 8 + (i & 7);         // 0..31 (128-col tiles)
    const int py = (j >> 2) * 8 + (i >> 3);       // 0..15 (256-row tiles)
    const int rowBase = py * 256;
    const int colBase = px * 128;

    if (tid < 256) {
        sq_r[tid]  = sq[rowBase + tid];
        lab_r[tid] = labels[rowBase + tid];
    } else if (tid < 384) {
        const int t = tid - 256;
        sq_c[t]  = sq[colBase + t];
        lab_c[t] = labels[colBase + t];
    }

    floatx16 acc[2][2];
    #pragma unroll
    for (int a = 0; a < 2; ++a)
        #pragma unroll
        for (int b = 0; b < 2; ++b)
            #pragma unroll
            for (int r = 0; r < 16; ++r) acc[a][b][r] = 0.f;

    auto stage = [&](int b, int kkv) {
        #pragma unroll
        for (int t = 0; t < 3; ++t) {
            const int s = wave * 3 + t;
            int kcl, p, row0, lofs;
            if (s < 16) {
                const int rq = s & 3;
                kcl  = s >> 2;
                p    = 2 * py + (rq >> 1);
                row0 = (rq & 1) * 64;
                lofs = (kcl * 256 + rq * 64) * 8;
            } else {
                const int u = s - 16;
                kcl  = u >> 1;
                p    = px;
                row0 = (u & 1) * 64;
                lofs = 8192 + (kcl * 128 + row0) * 8;
            }
            const int kc = (kcl < 2) ? (2 * kkv + kcl) : (64 + 2 * kkv + (kcl - 2));
            const _Float16* g = pan + ((size_t)(p * 128 + kc) * 128 + row0 + lane) * 8;
            GLD_LDS16(g, &S[b][lofs]);
        }
    };

    stage(0, 0);

    #pragma unroll 1
    for (int kk = 0; kk < 32; ++kk) {
        const int b = kk & 1;
        __syncthreads();
        if (kk + 1 < 32) stage(b ^ 1, kk + 1);
        const int rA = wr + mrow, cB = wc + mrow;
        const half8 ah0 = *(const half8*)&S[b][(half_id * 256 + rA) * 8];
        const half8 ah1 = *(const half8*)&S[b][(half_id * 256 + rA + 32) * 8];
        const half8 al0 = *(const half8*)&S[b][((2 + half_id) * 256 + rA) * 8];
        const half8 al1 = *(const half8*)&S[b][((2 + half_id) * 256 + rA + 32) * 8];
        const half8 bh0 = *(const half8*)&S[b][8192 + (half_id * 128 + cB) * 8];
        const half8 bh1 = *(const half8*)&S[b][8192 + (half_id * 128 + cB + 32) * 8];
        const half8 bl0 = *(const half8*)&S[b][8192 + ((2 + half_id) * 128 + cB) * 8];
        const half8 bl1 = *(const half8*)&S[b][8192 + ((2 + half_id) * 128 + cB + 32) * 8];
        acc[0][0] = __builtin_amdgcn_mfma_f32_32x32x16_f16(bh0, ah0, acc[0][0], 0, 0, 0);
        acc[0][1] = __builtin_amdgcn_mfma_f32_32x32x16_f16(bh0, ah1, acc[0][1], 0, 0, 0);
        acc[1][0] = __builtin_amdgcn_mfma_f32_32x32x16_f16(bh1, ah0, acc[1][0], 0, 0, 0);
        acc[1][1] = __builtin_amdgcn_mfma_f32_32x32x16_f16(bh1, ah1, acc[1][1], 0, 0, 0);
        acc[0][0] = __builtin_amdgcn_mfma_f32_32x32x16_f16(bl0, ah0, acc[0][0], 0, 0, 0);
        acc[0][1] = __builtin_amdgcn_mfma_f32_32x32x16_f16(bl0, ah1, acc[0][1], 0, 0, 0);
        acc[1][0] = __builtin_amdgcn_mfma_f32_32x32x16_f16(bl1, ah0, acc[1][0], 0, 0, 0);
        acc[1][1] = __builtin_amdgcn_mfma_f32_32x32x16_f16(bl1, ah1, acc[1][1], 0, 0, 0);
        acc[0][0] = __builtin_amdgcn_mfma_f32_32x32x16_f16(bh0, al0, acc[0][0], 0, 0, 0);
        acc[0][1] = __builtin_amdgcn_mfma_f32_32x32x16_f16(bh0, al1, acc[0][1], 0, 0, 0);
        acc[1][0] = __builtin_amdgcn_mfma_f32_32x32x16_f16(bh1, al0, acc[1][0], 0, 0, 0);
        acc[1][1] = __builtin_amdgcn_mfma_f32_32x32x16_f16(bh1, al1, acc[1][1], 0, 0, 0);
    }

    float sqr[2]; int labr[2];
    #pragma unroll
    for (int ai = 0; ai < 2; ++ai) {
        sqr[ai]  = sq_r[wr + ai * 32 + mrow];
        labr[ai] = lab_r[wr + ai * 32 + mrow];
    }

    #pragma unroll
    for (int ai = 0; ai < 2; ++ai) {
        float vp = 0.f, vn = 0.f;
        #pragma unroll
        for (int bj = 0; bj < 2; ++bj) {
            #pragma unroll
            for (int r = 0; r < 16; ++r) {
                const int c = wc + bj * 32 + (r & 3) + 8 * (r >> 2) + 4 * half_id;
                float d = sqrtf(fmaxf(sqr[ai] + sq_c[c] - 2.0f * acc[bj][ai][r], 1e-12f));
                const bool pos = (labr[ai] == lab_c[c]);
                vp = fmaxf(vp, pos ? d : 0.f);
                vn = fmaxf(vn, pos ? 0.f : d);
            }
        }
        vp = fmaxf(vp, __shfl_xor(vp, 32, 64));
        vn = fmaxf(vn, __shfl_xor(vn, 32, 64));
        if (half_id == 0) {
            atomicMax(&hp[rowBase + wr + ai * 32 + mrow],      __float_as_uint(vp));
            atomicMax(&hn_fall[rowBase + wr + ai * 32 + mrow], __float_as_uint(vn));
        }
    }

    __syncthreads();
    unsigned int* ctr = &bars[py * 32];
    if (tid == 0) {
        __threadfence();
        atomicAdd(ctr, 1u);
        while (__hip_atomic_load(ctr, __ATOMIC_ACQUIRE, __HIP_MEMORY_SCOPE_AGENT)
               < nrowblocks)
            __builtin_amdgcn_s_sleep(32);
    }
    __syncthreads();
    if (tid < 256)
        hp_r[tid] = __uint_as_float(__hip_atomic_load(&hp[rowBase + tid],
                                    __ATOMIC_RELAXED, __HIP_MEMORY_SCOPE_AGENT));
    __syncthreads();

    #pragma unroll
    for (int ai = 0; ai < 2; ++ai) {
        const float hpv = hp_r[wr + ai * 32 + mrow];
        float vm = __builtin_inff();
        #pragma unroll
        for (int bj = 0; bj < 2; ++bj) {
            #pragma unroll
            for (int r = 0; r < 16; ++r) {
                const int c = wc + bj * 32 + (r & 3) + 8 * (r >> 2) + 4 * half_id;
                float d = sqrtf(fmaxf(sqr[ai] + sq_c[c] - 2.0f * acc[bj][ai][r], 1e-12f));
                const bool cand = (labr[ai] != lab_c[c]) && (d > hpv);
                vm = fminf(vm, cand ? d : __builtin_inff());
            }
        }
        vm = fminf(vm, __shfl_xor(vm, 32, 64));
        if (half_id == 0)
            atomicMin(&hn_semi[rowBase + wr + ai * 32 + mrow], __float_as_uint(vm));
    }

    __syncthreads();
    if (tid == 0) {
        __threadfence();
        unsigned int old = atomicAdd(&bars[992], 1u);
        lastflag = (old == nblocks - 1) ? 1 : 0;
    }
    __syncthreads();
    if (!lastflag) return;
    if (tid == 0) __threadfence();
    __syncthreads();

    float* FS = (float*)&S[0][0];
    int*   IC = (int*)(FS + 512);
    int*   IA = IC + 512;
    int any = 0;
    for (int r = tid; r < N; r += 512) {
        float h  = __uint_as_float(__hip_atomic_load(&hp[r],      __ATOMIC_RELAXED, __HIP_MEMORY_SCOPE_AGENT));
        float hs = __uint_as_float(__hip_atomic_load(&hn_semi[r], __ATOMIC_RELAXED, __HIP_MEMORY_SCOPE_AGENT));
        any |= (hs < h + MARGIN) ? 1 : 0;
    }
    IA[tid] = any;
    __syncthreads();
    for (int s = 256; s; s >>= 1) {
        if (tid < s) IA[tid] |= IA[tid + s];
        __syncthreads();
    }
    const bool has_semi = IA[0] != 0;
    float sum = 0.f; int valid = 0;
    for (int r = tid; r < N; r += 512) {
        float h  = __uint_as_float(__hip_atomic_load(&hp[r], __ATOMIC_RELAXED, __HIP_MEMORY_SCOPE_AGENT));
        float hn = has_semi
            ? __uint_as_float(__hip_atomic_load(&hn_semi[r], __ATOMIC_RELAXED, __HIP_MEMORY_SCOPE_AGENT))
            : __uint_as_float(__hip_atomic_load(&hn_fall[r], __ATOMIC_RELAXED, __HIP_MEMORY_SCOPE_AGENT));
        float t = fmaxf(h - hn + MARGIN, 0.f);
        if (!(t > 0.f)) t = 0.f;        // -inf guard (hn=+inf rows)
        sum += t;
        valid += (t > 0.f) ? 1 : 0;
    }
    FS[tid] = sum; IC[tid] = valid;
    __syncthreads();
    for (int s = 256; s; s >>= 1) {
        if (tid < s) { FS[tid] += FS[tid + s]; IC[tid] += IC[tid + s]; }
        __syncthreads();
    }
    if (tid == 0) {
        float total = FS[0]; int v = IC[0];
        out[0] = (v > 0) ? (total / (float)v) : (total / (float)N);
    }
}

extern "C" void kernel_launch(void* const* d_in, const int* in_sizes, int n_in,
                              void* d_out, int out_size, void* d_ws, size_t ws_size,
                              hipStream_t stream) {
    const float* e      = (const float*)d_in[0];
    const int*   labels = (const int*)d_in[1];
    const int N = in_sizes[1];
    const int D = in_sizes[0] / N;
    float* out = (float*)d_out;

    float*        sq      = (float*)d_ws;
    unsigned int* hp      = (unsigned int*)d_ws + N;
    unsigned int* hn_fall = hp + N;
    unsigned int* hn_semi = hn_fall + N;
    unsigned int* bars    = hn_semi + N;     // 32 counters (128B-spaced) + done @992

    const size_t small_bytes = ((size_t)(4 * N + 1024) * 4 + 255) & ~(size_t)255;
    _Float16* pan = (_Float16*)((char*)d_ws + small_bytes);

    prep_kernel<<<N / 16, 256, 0, stream>>>(e, pan, sq, hp, hn_fall, hn_semi, bars, N, D);

    const int ntx = N / 128, nty = N / 256;  // 32 x 16 tiles = 512 blocks = 2/CU
    fused_kernel<<<ntx * nty, 512, 0, stream>>>(pan, labels, sq, hp, hn_fall, hn_semi,
                                                bars, out, N, D,
                                                (unsigned)ntx, (unsigned)(ntx * nty));
}